// Round 5
// baseline (869.201 us; speedup 1.0000x reference)
//
#include <hip/hip_runtime.h>
#include <hip/hip_bf16.h>

// SAGEConv: out = x @ W_self^T + b_self + segsum(x[col]*w, row) @ W_neigh^T + b_neigh
// N=100000, E=1600000, C=64. fp32 tensors; edge_index int32 [2*E] (dst|src); out fp32.
//
// R5: R2-vs-R4 evidence: coalesced full-line memory ops run ~10x faster per line
// than per-lane scattered 8B ops. So: coarse 128-node-bucket sort with LDS-staged
// COALESCED writes, then per-bucket LDS fp32 tile aggregation (ds_add_f32,
// bank-conflict-free), no global fp32 atomics, no fine sort.

#define C 64
#define BKT 128                 // nodes per bucket
#define MAXB 800                // max bucket count supported by static LDS
#define BINT 6144               // edges per bin block (24 per thread)

typedef __attribute__((ext_vector_type(8))) short bf16x8;
typedef __attribute__((ext_vector_type(4))) float f32x4;

__device__ inline unsigned short f2bf(float f) {
    union { __hip_bfloat16 h; unsigned short u; } c;
    c.h = __float2bfloat16(f);
    return c.u;
}

// --------------------------------------------------------------------------
// prep: bucket histogram (LDS pre-agg) + x -> bf16 conversion.
// --------------------------------------------------------------------------
__global__ __launch_bounds__(256) void prep_kernel(
        const int* __restrict__ ei, int* __restrict__ bhist, int E, int NBK,
        const float* __restrict__ x, unsigned short* __restrict__ xb, int n4) {
    __shared__ int lh[MAXB];
    const int t = threadIdx.x;
    for (int i = t; i < NBK; i += 256) lh[i] = 0;
    __syncthreads();
    const int gtid = blockIdx.x * 256 + t;
    const int gs = gridDim.x * 256;
    for (int e = gtid; e < E; e += gs)
        atomicAdd(&lh[ei[e] >> 7], 1);
    __syncthreads();
    for (int i = t; i < NBK; i += 256)
        if (lh[i]) atomicAdd(&bhist[i], lh[i]);
    // x conversion (independent of hist)
    const float4* x4 = (const float4*)x;
    ushort4* xb4 = (ushort4*)xb;
    for (int i = gtid; i < n4; i += gs) {
        float4 v = x4[i];
        ushort4 o;
        o.x = f2bf(v.x); o.y = f2bf(v.y); o.z = f2bf(v.z); o.w = f2bf(v.w);
        xb4[i] = o;
    }
}

// --------------------------------------------------------------------------
// scan: exclusive scan of bhist[NBK] -> boffs[NBK+1], copy to bcur. 1 block.
// --------------------------------------------------------------------------
__global__ __launch_bounds__(1024) void scan_kernel(
        const int* __restrict__ bhist, int* __restrict__ boffs,
        int* __restrict__ bcur, int NBK) {
    __shared__ int s[1024];
    const int t = threadIdx.x;
    s[t] = (t < NBK) ? bhist[t] : 0;
    __syncthreads();
    for (int off = 1; off < 1024; off <<= 1) {
        int v = 0;
        if (t >= off) v = s[t - off];
        __syncthreads();
        if (t >= off) s[t] += v;
        __syncthreads();
    }
    if (t < NBK) {
        int e = (t > 0) ? s[t - 1] : 0;
        boffs[t] = e;
        bcur[t] = e;
        if (t == NBK - 1) boffs[NBK] = s[t];
    }
}

// --------------------------------------------------------------------------
// bin: coarse counting sort by bucket, LDS-staged for coalesced global writes.
// Per block: hist -> block scan -> bulk global reservation (1 atomic/bucket)
// -> LDS scatter -> sequential write-out (binary search for bucket id).
// --------------------------------------------------------------------------
__global__ __launch_bounds__(256) void bin_kernel(
        const int* __restrict__ ei, const float* __restrict__ ew,
        int* __restrict__ bcur, const int* __restrict__ unused,
        int2* __restrict__ sorted, int E, int NBK) {
    __shared__ int2 stage[BINT];            // 48 KB
    __shared__ int h[MAXB];
    __shared__ int ls[MAXB + 1];
    __shared__ int gb[MAXB];
    __shared__ int cur[MAXB];
    __shared__ int part[256];

    const int t = threadIdx.x;
    const int e0 = blockIdx.x * BINT;
    const int cnt = min(BINT, E - e0);

    for (int i = t; i < NBK; i += 256) h[i] = 0;
    __syncthreads();

    // phase 1: local histogram (coalesced dst reads)
#pragma unroll
    for (int k = 0; k < BINT / 256; ++k) {
        const int e = e0 + t + k * 256;
        if (e - e0 < cnt) atomicAdd(&h[ei[e] >> 7], 1);
    }
    __syncthreads();

    // phase 2: block scan of h -> ls (thread owns 4 consecutive buckets)
    int vloc[4]; int s0 = 0;
#pragma unroll
    for (int k = 0; k < 4; ++k) {
        const int idx = t * 4 + k;
        vloc[k] = (idx < NBK) ? h[idx] : 0;
        s0 += vloc[k];
    }
    part[t] = s0;
    __syncthreads();
    for (int off = 1; off < 256; off <<= 1) {
        int v = 0;
        if (t >= off) v = part[t - off];
        __syncthreads();
        if (t >= off) part[t] += v;
        __syncthreads();
    }
    int run = (t > 0) ? part[t - 1] : 0;
#pragma unroll
    for (int k = 0; k < 4; ++k) {
        const int idx = t * 4 + k;
        if (idx < NBK) ls[idx] = run;
        run += vloc[k];
    }
    if (t == 255) ls[NBK] = part[255];      // == cnt
    __syncthreads();

    // phase 2b: reserve global space, one atomic per non-empty bucket
    for (int i = t; i < NBK; i += 256) {
        const int hh = ls[i + 1] - ls[i];
        gb[i] = hh ? atomicAdd(&bcur[i], hh) : 0;
        cur[i] = ls[i];
    }
    __syncthreads();

    // phase 3: LDS scatter into bucket-sorted staging
#pragma unroll
    for (int k = 0; k < BINT / 256; ++k) {
        const int e = e0 + t + k * 256;
        if (e - e0 < cnt) {
            const int d = ei[e];
            const int s = ei[E + e];
            const float w = ew[e];
            const int b = d >> 7;
            const int dl = d & 127;
            const int p = atomicAdd(&cur[b], 1);
            stage[p] = make_int2((dl << 17) | s, __float_as_int(w));
        }
    }
    __syncthreads();

    // phase 4: sequential write-out; bucket of slot i via binary search in ls
    for (int i = t; i < cnt; i += 256) {
        int lo = 0, hi = NBK - 1;
#pragma unroll
        for (int it = 0; it < 10; ++it) {   // 2^10 >= 800
            const int mid = (lo + hi + 1) >> 1;
            if (ls[mid] <= i) lo = mid; else hi = mid - 1;
        }
        sorted[gb[lo] + (i - ls[lo])] = stage[i];
    }
}

// --------------------------------------------------------------------------
// agg: one block per bucket; 128x64 fp32 tile in LDS (32 KB). One wave per
// edge: wave-uniform meta (s_load), lane=channel 2B bf16 gather (one 128B row
// per instr), ds_add_f32 into tile (lane-consecutive -> 2-way -> free).
// --------------------------------------------------------------------------
__global__ __launch_bounds__(256) void agg_kernel(
        const unsigned short* __restrict__ xb,
        const int2* __restrict__ sorted,
        const int* __restrict__ boffs,
        float* __restrict__ agg, int N) {
    __shared__ float tile[BKT * C];         // 32 KB
    const int t = threadIdx.x;
    const int b = blockIdx.x;
    const int node0 = b << 7;

    float4* tile4 = (float4*)tile;
#pragma unroll
    for (int i = t; i < BKT * C / 4; i += 256) tile4[i] = make_float4(0.f, 0.f, 0.f, 0.f);
    __syncthreads();

    const int lane = t & 63;
    const int wv = __builtin_amdgcn_readfirstlane(t >> 6);   // wave-uniform
    const int beg = boffs[b];
    const int end = boffs[b + 1];

#pragma unroll 4
    for (int j = beg + wv; j < end; j += 4) {
        const int2 m = sorted[j];                       // wave-uniform -> s_load
        const int dl = m.x >> 17;
        const int src = m.x & 0x1FFFF;
        const float w = __int_as_float(m.y);
        const unsigned short us = xb[(size_t)src * C + lane];   // 128B row/instr
        const float xv = __int_as_float(((int)us) << 16);
        atomicAdd(&tile[dl * C + lane], w * xv);        // ds_add_f32, bank-free
    }
    __syncthreads();

    // writeback (coalesced float4); covers every row -> no agg memset needed
    const int rows = min(BKT, N - node0);
    float4* agg4 = (float4*)(agg + (size_t)node0 * C);
    for (int i = t; i < rows * (C / 4); i += 256)
        agg4[i] = tile4[i];
}

// --------------------------------------------------------------------------
// fallback (ws too small / N too big): R2 atomic scatter.
// --------------------------------------------------------------------------
__global__ __launch_bounds__(256) void scatter_kernel(
        const float* __restrict__ x, const int* __restrict__ ei,
        const float* __restrict__ ew, float* __restrict__ agg, int E) {
    const int lane = threadIdx.x & 63;
    const int wid = (blockIdx.x * blockDim.x + threadIdx.x) >> 6;
    const int nw = (gridDim.x * blockDim.x) >> 6;
    for (int base = wid * 64; base < E; base += nw * 64) {
        const int e = base + lane;
        int dst = 0, src = 0; float w = 0.f;
        if (e < E) { dst = ei[e]; src = ei[E + e]; w = ew[e]; }
        const int cnt = min(64, E - base);
        for (int j = 0; j < cnt; ++j) {
            const int d = __shfl(dst, j);
            const int s = __shfl(src, j);
            const float wj = __shfl(w, j);
            atomicAdd(&agg[d * C + lane], x[s * C + lane] * wj);
        }
    }
}

// --------------------------------------------------------------------------
// proj: out = [x | agg] @ [Ws | Wn]^T + bias as K=128 bf16 MFMA GEMM.
// --------------------------------------------------------------------------
__device__ inline bf16x8 cvt8(const float* __restrict__ p) {
    f32x4 lo = *(const f32x4*)p;
    f32x4 hi = *(const f32x4*)(p + 4);
    union { bf16x8 v; __hip_bfloat16 e[8]; } u;
#pragma unroll
    for (int j = 0; j < 4; ++j) u.e[j] = __float2bfloat16(lo[j]);
#pragma unroll
    for (int j = 0; j < 4; ++j) u.e[4 + j] = __float2bfloat16(hi[j]);
    return u.v;
}

__global__ __launch_bounds__(256) void proj_kernel(
        const float* __restrict__ x, const float* __restrict__ agg,
        const float* __restrict__ Ws, const float* __restrict__ bs,
        const float* __restrict__ Wn, const float* __restrict__ bn,
        float* __restrict__ out, int N) {
    const int lane = threadIdx.x & 63;
    const int wid = (blockIdx.x * blockDim.x + threadIdx.x) >> 6;
    const int l15 = lane & 15;
    const int quad = lane >> 4;
    const int nTiles = N >> 4;
    if (wid >= nTiles) return;
    const int m0 = wid << 4;

    bf16x8 bsf[4][2], bnf[4][2];
#pragma unroll
    for (int tt = 0; tt < 4; ++tt) {
        const int o = tt * 16 + l15;
#pragma unroll
        for (int h = 0; h < 2; ++h) {
            bsf[tt][h] = cvt8(Ws + o * C + h * 32 + quad * 8);
            bnf[tt][h] = cvt8(Wn + o * C + h * 32 + quad * 8);
        }
    }

    const int m = m0 + l15;
    bf16x8 ax[2], ag[2];
#pragma unroll
    for (int h = 0; h < 2; ++h) {
        ax[h] = cvt8(x + m * C + h * 32 + quad * 8);
        ag[h] = cvt8(agg + m * C + h * 32 + quad * 8);
    }

#pragma unroll
    for (int tt = 0; tt < 4; ++tt) {
        f32x4 acc = {0.f, 0.f, 0.f, 0.f};
        acc = __builtin_amdgcn_mfma_f32_16x16x32_bf16(ax[0], bsf[tt][0], acc, 0, 0, 0);
        acc = __builtin_amdgcn_mfma_f32_16x16x32_bf16(ax[1], bsf[tt][1], acc, 0, 0, 0);
        acc = __builtin_amdgcn_mfma_f32_16x16x32_bf16(ag[0], bnf[tt][0], acc, 0, 0, 0);
        acc = __builtin_amdgcn_mfma_f32_16x16x32_bf16(ag[1], bnf[tt][1], acc, 0, 0, 0);
        const int o = tt * 16 + l15;
        const float bias = bs[o] + bn[o];
#pragma unroll
        for (int r = 0; r < 4; ++r)
            out[(m0 + quad * 4 + r) * C + o] = acc[r] + bias;
    }
}

extern "C" void kernel_launch(void* const* d_in, const int* in_sizes, int n_in,
                              void* d_out, int out_size, void* d_ws, size_t ws_size,
                              hipStream_t stream) {
    const float* x  = (const float*)d_in[0];
    const int*   ei = (const int*)d_in[1];
    const float* ew = (const float*)d_in[2];
    const float* Ws = (const float*)d_in[3];
    const float* bs = (const float*)d_in[4];
    const float* Wn = (const float*)d_in[5];
    const float* bn = (const float*)d_in[6];

    const int N = in_sizes[0] / C;   // 100000
    const int E = in_sizes[2];       // 1600000
    const int NBK = (N + BKT - 1) / BKT;   // 782

    // Workspace layout
    char* p = (char*)d_ws;
    float* agg = (float*)p;                 p += (size_t)N * C * sizeof(float);   // 25.6MB
    unsigned short* xb = (unsigned short*)p; p += (size_t)N * C * sizeof(short);  // 12.8MB
    int2* sorted = (int2*)p;                p += (size_t)E * sizeof(int2);        // 12.8MB
    int* bhist = (int*)p;                   p += (size_t)MAXB * sizeof(int);
    int* boffs = (int*)p;                   p += (size_t)(MAXB + 1) * sizeof(int);
    int* bcur = (int*)p;                    p += (size_t)MAXB * sizeof(int);
    const size_t needed = (size_t)(p - (char*)d_ws);

    const int nTiles = N / 16;
    const int projBlocks = (nTiles + 3) / 4;

    // CSR path requires src to fit 17 bits and NBK within static LDS arrays
    if (needed <= ws_size && N <= (1 << 17) && NBK <= MAXB) {
        const int n4 = N * C / 4;
        hipMemsetAsync(bhist, 0, (size_t)NBK * sizeof(int), stream);
        prep_kernel<<<256, 256, 0, stream>>>(ei, bhist, E, NBK, x, xb, n4);
        scan_kernel<<<1, 1024, 0, stream>>>(bhist, boffs, bcur, NBK);
        bin_kernel<<<(E + BINT - 1) / BINT, 256, 0, stream>>>(ei, ew, bcur, bhist,
                                                              sorted, E, NBK);
        agg_kernel<<<NBK, 256, 0, stream>>>(xb, sorted, boffs, agg, N);
    } else {
        hipMemsetAsync(agg, 0, (size_t)N * C * sizeof(float), stream);
        scatter_kernel<<<2048, 256, 0, stream>>>(x, ei, ew, agg, E);
    }

    proj_kernel<<<projBlocks, 256, 0, stream>>>(x, agg, Ws, bs, Wn, bn,
                                                (float*)d_out, N);
}